// Round 1
// baseline (133.770 us; speedup 1.0000x reference)
//
#include <hip/hip_runtime.h>
#include <math.h>

#define Ec 256
#define Sc 512
#define Bc 2
#define Hc 8
#define Dc 32
#define MAXNORM (1.0f - 1e-5f)
#define NEc (Bc * Sc * Ec)
#define KSQ 2                  // K-split for qkv GEMM (nk=2 chunks of 64)
#define KSO 4                  // K-split for proj GEMM (nk=1)
#define NROWS (Bc * Hc * Sc)   // 8192 (b,h,s) rows

__device__ __forceinline__ float fullWaveSum(float v) {
#pragma unroll
  for (int m = 32; m >= 1; m >>= 1) v += __shfl_xor(v, m, 64);
  return v;
}
__device__ __forceinline__ float halfWaveSum(float v) {
#pragma unroll
  for (int m = 16; m >= 1; m >>= 1) v += __shfl_xor(v, m, 64);
  return v;
}
__device__ __forceinline__ float atanh_fast(float z) {   // z in [0, 1)
  return 0.5f * __logf((1.0f + z) / (1.0f - z));
}
__device__ __forceinline__ float tanh_fast(float a) {    // a >= 0
  float e = __expf(-2.0f * a);
  return (1.0f - e) / (1.0f + e);
}

// ---------------------------------------------------------------------------
// Tiled GEMM partial: O[kz] = X[:, kz*64*nk : (kz+1)*64*nk] @ W[:, same]^T
// Tile 32 rows x 64 cols, nk K-chunks of 64. blk 128.
// ---------------------------------------------------------------------------
__global__ __launch_bounds__(128) void gemm_xwt(
    const float* __restrict__ X,
    const float* __restrict__ W0, const float* __restrict__ W1,
    const float* __restrict__ W2,
    float* __restrict__ O0, float* __restrict__ O1, float* __restrict__ O2,
    const int nk) {
  const int tid = threadIdx.x;
  const int bx = blockIdx.x;
  const int by = blockIdx.y;
  const int kz = blockIdx.z;
  const int mat = by >> 2;
  const int cb0 = (by & 3) * 64;
  const int rb0 = bx * 32;
  const int kk0 = kz * 64 * nk;
  const float* __restrict__ W = (mat == 0) ? W0 : (mat == 1) ? W1 : W2;
  float* __restrict__ O = ((mat == 0) ? O0 : (mat == 1) ? O1 : O2) + (size_t)kz * NEc;

  __shared__ float Xs[64][36];   // [k][row]
  __shared__ float Ws[64][68];   // [k][col]

  const int f4 = tid & 15;
  const int sub = tid >> 4;
  const int ty = tid >> 4;
  const int tx = tid & 15;

  float acc[4][4];
#pragma unroll
  for (int i = 0; i < 4; ++i)
#pragma unroll
    for (int j = 0; j < 4; ++j) acc[i][j] = 0.f;

  for (int c = 0; c < nk; ++c) {
    const int kk = kk0 + c * 64;
    __syncthreads();
#pragma unroll
    for (int i = 0; i < 4; ++i) {
      int row = sub + i * 8;
      float4 v = *(const float4*)&X[(size_t)(rb0 + row) * Ec + kk + f4 * 4];
      Xs[f4 * 4 + 0][row] = v.x;
      Xs[f4 * 4 + 1][row] = v.y;
      Xs[f4 * 4 + 2][row] = v.z;
      Xs[f4 * 4 + 3][row] = v.w;
    }
#pragma unroll
    for (int i = 0; i < 8; ++i) {
      int col = sub + i * 8;
      float4 v = *(const float4*)&W[(size_t)(cb0 + col) * Ec + kk + f4 * 4];
      Ws[f4 * 4 + 0][col] = v.x;
      Ws[f4 * 4 + 1][col] = v.y;
      Ws[f4 * 4 + 2][col] = v.z;
      Ws[f4 * 4 + 3][col] = v.w;
    }
    __syncthreads();
#pragma unroll 8
    for (int k = 0; k < 64; ++k) {
      float4 a = *(const float4*)&Xs[k][ty * 4];
      float4 b = *(const float4*)&Ws[k][tx * 4];
      float av[4] = {a.x, a.y, a.z, a.w};
      float bv[4] = {b.x, b.y, b.z, b.w};
#pragma unroll
      for (int i = 0; i < 4; ++i)
#pragma unroll
        for (int j = 0; j < 4; ++j) acc[i][j] = fmaf(av[i], bv[j], acc[i][j]);
    }
  }
#pragma unroll
  for (int i = 0; i < 4; ++i) {
    float4 o = make_float4(acc[i][0], acc[i][1], acc[i][2], acc[i][3]);
    *(float4*)&O[(size_t)(rb0 + ty * 4 + i) * Ec + cb0 + tx * 4] = o;
  }
}

// ---------------------------------------------------------------------------
// Per-row hyp_linear epilogue for q/k/v (sums the KSQ K-split partials)
// ---------------------------------------------------------------------------
__global__ __launch_bounds__(256) void qkv_stats(
    const float* __restrict__ x,
    const float* __restrict__ mxq, const float* __restrict__ mxk,
    const float* __restrict__ mxv,
    const float* __restrict__ bq, const float* __restrict__ bk,
    const float* __restrict__ bv,
    float* __restrict__ qo, float* __restrict__ ko, float* __restrict__ lvo,
    float* __restrict__ qno, float* __restrict__ kno) {
  const int t = threadIdx.x;
  const int row = blockIdx.x;
  const int b = row >> 9;
  const int s = row & (Sc - 1);
  const size_t idx = (size_t)row * Ec + t;
  const float xv = x[idx];
  float mq = 0.f, mk = 0.f, mv = 0.f;
#pragma unroll
  for (int p = 0; p < KSQ; ++p) {
    mq += mxq[idx + (size_t)p * NEc];
    mk += mxk[idx + (size_t)p * NEc];
    mv += mxv[idx + (size_t)p * NEc];
  }
  const float bb[3] = {bq[t], bk[t], bv[t]};
  const float mvals[3] = {mq, mk, mv};

  float vals[10] = {xv * xv,
                    mq * mq, mq * bb[0], bb[0] * bb[0],
                    mk * mk, mk * bb[1], bb[1] * bb[1],
                    mv * mv, mv * bb[2], bb[2] * bb[2]};
  __shared__ float red[10][4];
  __shared__ float fin[10];
#pragma unroll
  for (int i = 0; i < 10; ++i) {
    float v = fullWaveSum(vals[i]);
    if ((t & 63) == 0) red[i][t >> 6] = v;
  }
  __syncthreads();
  if (t < 10) fin[t] = red[t][0] + red[t][1] + red[t][2] + red[t][3];
  __syncthreads();

  const float x2 = fin[0];
  const float xn = sqrtf(fmaxf(x2, 1e-15f));
  const float at = atanh_fast(fminf(xn, MAXNORM));  // SC = 1
  const int h = t >> 5;

#pragma unroll
  for (int m = 0; m < 3; ++m) {
    float mx2 = fin[1 + 3 * m];
    float mxb = fin[2 + 3 * m];
    float b2 = fin[3 + 3 * m];
    float mxn = sqrtf(fmaxf(mx2, 1e-15f));
    float scl = tanh_fast((mxn / xn) * at) / mxn;
    float mvv = scl * mvals[m];
    float X2 = scl * scl * mx2;
    float XY = scl * mxb;
    float numc = 1.0f + 2.0f * XY + b2;
    float den = 1.0f + 2.0f * XY + X2 * b2 + 1e-15f;
    float res = (numc * mvv + (1.0f - X2) * bb[m]) / den;
    if (m < 2) {
      res = fminf(res, MAXNORM);                 // elementwise clamp_max
      float s2 = halfWaveSum(res * res);         // per-head ||.||^2 (C=1)
      if (m == 0) {
        qo[idx] = res;
        if ((t & 31) == 0) qno[(b * Hc + h) * Sc + s] = s2;
      } else {
        ko[idx] = res;
        if ((t & 31) == 0) kno[(b * Hc + h) * Sc + s] = s2;
      }
    } else {
      float vn2 = halfWaveSum(res * res);
      float vn = sqrtf(fmaxf(vn2, 1e-15f));
      float f = atanh_fast(fminf(vn, MAXNORM)) / vn;  // logmap0 factor
      lvo[idx] = f * res;
    }
  }
}

// ---------------------------------------------------------------------------
// Fused attention: per block = 16 q-rows of one (b,h); sweep 8 k-tiles of 64.
// QK^T (from LDS-transposed tiles) -> hyperbolic-distance epilogue ->
// p-tile transposed through LDS -> PV accumulate in registers.
// p = z^sinv is in (0,1], so no online-max: accumulate num/den, divide once.
// Ends with softmax-normalize + expmap0, writes attention output directly.
// grid (32 sq-tiles, 16 bh) = 512 blocks, blk 256 (2 blocks/CU, 2 waves/SIMD).
// ---------------------------------------------------------------------------
__global__ __launch_bounds__(256) void attn_fused(
    const float* __restrict__ q, const float* __restrict__ k,
    const float* __restrict__ lv, const float* __restrict__ qn,
    const float* __restrict__ kn, const float* __restrict__ hs,
    float* __restrict__ out) {
  const int tid = threadIdx.x;
  const int sq0 = blockIdx.x * 16;
  const int bh = blockIdx.y;
  const int b = bh >> 3;
  const int h = bh & 7;

  __shared__ float Qst[Dc][17];      // [d][r]  transposed q-tile
  __shared__ float Kst[Dc][68];      // [d][j]  transposed k-tile (float4-aligned rows)
  __shared__ float LVs[2][64][36];   // [j][d]  row-major lv-tile, double-buffered
  __shared__ float Pst[64][17];      // [j][r]  transposed p-tile
  __shared__ float knS[64];
  __shared__ float redD[4][16];
  __shared__ float redN[4][16];

  const int r = tid & 15;            // q-row (QK and PV mappings share r)
  const int c4 = tid >> 4;           // QK: col-quad; PV: dim-pair index

  // stage Q transposed (16 rows x 32 dims), once
  if (tid < 128) {
    int qr = tid >> 3, dq = tid & 7;
    float4 v = *(const float4*)&q[(size_t)(b * Sc + sq0 + qr) * Ec + h * Dc + dq * 4];
    Qst[dq * 4 + 0][qr] = v.x;
    Qst[dq * 4 + 1][qr] = v.y;
    Qst[dq * 4 + 2][qr] = v.z;
    Qst[dq * 4 + 3][qr] = v.w;
  }
  const float q2 = qn[bh * Sc + sq0 + r];
  const float omq = 1.0f - q2;
  const float sinv = -1.0f / (hs[h] * sqrtf((float)Dc));

  float out0 = 0.f, out1 = 0.f, den_acc = 0.f;

  const int srow = tid >> 3;         // 0..31  (staging row)
  const int sdq = tid & 7;           // 0..7   (staging dim-quad)

  for (int t = 0; t < 8; ++t) {
    const int j0 = t * 64;
    const int buf = t & 1;
    // ---- stage K (transposed) + LV (row-major, other buffer) + kn ----
#pragma unroll
    for (int i = 0; i < 2; ++i) {
      int row = srow + i * 32;
      const size_t gidx = (size_t)(b * Sc + j0 + row) * Ec + h * Dc + sdq * 4;
      float4 kv = *(const float4*)&k[gidx];
      Kst[sdq * 4 + 0][row] = kv.x;
      Kst[sdq * 4 + 1][row] = kv.y;
      Kst[sdq * 4 + 2][row] = kv.z;
      Kst[sdq * 4 + 3][row] = kv.w;
      float4 lvv = *(const float4*)&lv[gidx];
      *(float4*)&LVs[buf][row][sdq * 4] = lvv;
    }
    if (tid < 64) knS[tid] = kn[bh * Sc + j0 + tid];
    __syncthreads();   // stage visible; also: all prior-iter PV reads done

    // ---- QK: p[r][c4*4+j] over K=32 ----
    float p[4] = {0.f, 0.f, 0.f, 0.f};
#pragma unroll
    for (int kk = 0; kk < Dc; ++kk) {
      float qv = Qst[kk][r];
      float4 kvv = *(const float4*)&Kst[kk][c4 * 4];
      p[0] = fmaf(qv, kvv.x, p[0]);
      p[1] = fmaf(qv, kvv.y, p[1]);
      p[2] = fmaf(qv, kvv.z, p[2]);
      p[3] = fmaf(qv, kvv.w, p[3]);
    }
    // ---- epilogue: hyperbolic distance -> p = z^sinv (native log2/exp2) ----
    float4 k2v = *(const float4*)&knS[c4 * 4];
    float kk2[4] = {k2v.x, k2v.y, k2v.z, k2v.w};
    float ps = 0.f;
#pragma unroll
    for (int j = 0; j < 4; ++j) {
      const float k2 = kk2[j];
      const float kq = p[j];
      const float omk = 1.0f - k2;
      float s2x2 = fmaf(-4.0f, kq, 2.0f * k2 + 2.0f * q2);     // 2*||q-k||^2
      float dden = fmaf(k2, q2, fmaf(-2.0f, kq, 1.0f)) + 1e-15f;
      float Pd = fmaf(dden, omk * omq, 1e-20f);
      float rp = __builtin_amdgcn_rcpf(Pd);
      float tt = fmaxf(s2x2 * rp, 1e-7f);                      // a-1
      float z = (1.0f + tt) + sqrtf(fmaf(tt, tt, tt + tt));
      float po = __builtin_amdgcn_exp2f(sinv * __builtin_amdgcn_logf(z));
      Pst[c4 * 4 + j][r] = po;
      ps += po;
    }
    den_acc += ps;
    __syncthreads();   // Pst complete; epilogue's Kst/knS reads done

    // ---- PV: out[r][c4*2 .. +1] += sum_j p[r][j] * lv[j][d] ----
#pragma unroll 8
    for (int j = 0; j < 64; ++j) {
      float pj = Pst[j][r];
      float2 l2 = *(const float2*)&LVs[buf][j][c4 * 2];
      out0 = fmaf(pj, l2.x, out0);
      out1 = fmaf(pj, l2.y, out1);
    }
    // no barrier: next stage writes Kst/knS (not read by PV) and LVs[buf^1];
    // Pst is only rewritten after the next __syncthreads.
  }

  // ---- softmax denominator: reduce den_acc across 16 c4-groups per row ----
  float d = den_acc;
  d += __shfl_xor(d, 16, 64);
  d += __shfl_xor(d, 32, 64);
  const int wv = tid >> 6;
  if ((tid & 63) < 16) redD[wv][r] = d;
  __syncthreads();
  const float den = redD[0][r] + redD[1][r] + redD[2][r] + redD[3][r];
  const float li = 1.0f / den;
  float o0 = out0 * li, o1 = out1 * li;

  // ---- expmap0: per-row norm over 32 dims (16 dim-pair threads) ----
  float un2 = fmaf(o0, o0, o1 * o1);
  un2 += __shfl_xor(un2, 16, 64);
  un2 += __shfl_xor(un2, 32, 64);
  if ((tid & 63) < 16) redN[wv][r] = un2;
  __syncthreads();
  un2 = redN[0][r] + redN[1][r] + redN[2][r] + redN[3][r];
  float un = sqrtf(fmaxf(un2, 1e-15f));
  float f = tanh_fast(un) / un;    // expmap0 factor (SC = 1)
  float2 ov = make_float2(o0 * f, o1 * f);
  *(float2*)&out[(size_t)(b * Sc + sq0 + r) * Ec + h * Dc + c4 * 2] = ov;
}

// ---------------------------------------------------------------------------
// Per-row hyp_linear epilogue for the output projection (sums KSO partials)
// ---------------------------------------------------------------------------
__global__ __launch_bounds__(256) void proj_stats(
    const float* __restrict__ xin, const float* __restrict__ mx,
    const float* __restrict__ bo, float* __restrict__ out) {
  const int t = threadIdx.x;
  const int row = blockIdx.x;
  const size_t idx = (size_t)row * Ec + t;
  const float xv = xin[idx];
  float m = 0.f;
#pragma unroll
  for (int p = 0; p < KSO; ++p) m += mx[idx + (size_t)p * NEc];
  const float bb = bo[t];
  float vals[4] = {xv * xv, m * m, m * bb, bb * bb};
  __shared__ float red[4][4];
  __shared__ float fin[4];
#pragma unroll
  for (int i = 0; i < 4; ++i) {
    float v = fullWaveSum(vals[i]);
    if ((t & 63) == 0) red[i][t >> 6] = v;
  }
  __syncthreads();
  if (t < 4) fin[t] = red[t][0] + red[t][1] + red[t][2] + red[t][3];
  __syncthreads();

  float x2 = fin[0], mx2 = fin[1], mxb = fin[2], b2 = fin[3];
  float xn = sqrtf(fmaxf(x2, 1e-15f));
  float mxn = sqrtf(fmaxf(mx2, 1e-15f));
  float scl = tanh_fast((mxn / xn) * atanh_fast(fminf(xn, MAXNORM))) / mxn;
  float mvv = scl * m;
  float X2 = scl * scl * mx2;
  float XY = scl * mxb;
  float numc = 1.0f + 2.0f * XY + b2;
  float den = 1.0f + 2.0f * XY + X2 * b2 + 1e-15f;
  out[idx] = (numc * mvv + (1.0f - X2) * bb) / den;
}

extern "C" void kernel_launch(void* const* d_in, const int* in_sizes, int n_in,
                              void* d_out, int out_size, void* d_ws, size_t ws_size,
                              hipStream_t stream) {
  (void)in_sizes; (void)n_in; (void)out_size; (void)ws_size;
  const float* x  = (const float*)d_in[0];
  const float* Wq = (const float*)d_in[1];
  const float* bq = (const float*)d_in[2];
  const float* Wk = (const float*)d_in[3];
  const float* bk = (const float*)d_in[4];
  const float* Wv = (const float*)d_in[5];
  const float* bv = (const float*)d_in[6];
  const float* Wo = (const float*)d_in[7];
  const float* bo = (const float*)d_in[8];
  const float* hs = (const float*)d_in[9];

  float* ws = (float*)d_ws;
  const int NE = NEc;            // 262144
  const int NH = NROWS;          // 8192
  float* mxq = ws;               // KSQ*NE partials each
  float* mxk = mxq + KSQ * NE;
  float* mxv = mxk + KSQ * NE;
  float* mxo = mxv + KSQ * NE;   // KSO*NE partials
  float* qb  = mxo + KSO * NE;
  float* kb  = qb + NE;
  float* lvb = kb + NE;
  float* aob = lvb + NE;
  float* qnb = aob + NE;
  float* knb = qnb + NH;

  const int M = Bc * Sc;  // 1024 rows

  gemm_xwt<<<dim3(M / 32, 12, KSQ), 128, 0, stream>>>(x, Wq, Wk, Wv,
                                                      mxq, mxk, mxv, 2);
  qkv_stats<<<M, 256, 0, stream>>>(x, mxq, mxk, mxv, bq, bk, bv,
                                   qb, kb, lvb, qnb, knb);
  attn_fused<<<dim3(32, 16), 256, 0, stream>>>(qb, kb, lvb, qnb, knb, hs, aob);
  gemm_xwt<<<dim3(M / 32, 4, KSO), 128, 0, stream>>>(aob, Wo, Wo, Wo,
                                                     mxo, mxo, mxo, 1);
  proj_stats<<<M, 256, 0, stream>>>(aob, mxo, bo, (float*)d_out);
}

// Round 2
// 124.563 us; speedup vs baseline: 1.0739x; 1.0739x over previous
//
#include <hip/hip_runtime.h>
#include <math.h>

#define Ec 256
#define Sc 512
#define Bc 2
#define Hc 8
#define Dc 32
#define MAXNORM (1.0f - 1e-5f)
#define NEc (Bc * Sc * Ec)
#define KSQ 2                  // K-split for qkv GEMM (nk=2 chunks of 64)
#define KSO 4                  // K-split for proj GEMM (nk=1)
#define NROWS (Bc * Hc * Sc)   // 8192 (b,h,s) rows
#define KT 128                 // fused-attn k-tile
#define NT (Sc / KT)           // 4 tiles

__device__ __forceinline__ float fullWaveSum(float v) {
#pragma unroll
  for (int m = 32; m >= 1; m >>= 1) v += __shfl_xor(v, m, 64);
  return v;
}
__device__ __forceinline__ float halfWaveSum(float v) {
#pragma unroll
  for (int m = 16; m >= 1; m >>= 1) v += __shfl_xor(v, m, 64);
  return v;
}
__device__ __forceinline__ float atanh_fast(float z) {   // z in [0, 1)
  return 0.5f * __logf((1.0f + z) / (1.0f - z));
}
__device__ __forceinline__ float tanh_fast(float a) {    // a >= 0
  float e = __expf(-2.0f * a);
  return (1.0f - e) / (1.0f + e);
}

// ---------------------------------------------------------------------------
// Tiled GEMM partial: O[kz] = X[:, kz*64*nk : (kz+1)*64*nk] @ W[:, same]^T
// Tile 32 rows x 64 cols, nk K-chunks of 64. blk 128.
// ---------------------------------------------------------------------------
__global__ __launch_bounds__(128) void gemm_xwt(
    const float* __restrict__ X,
    const float* __restrict__ W0, const float* __restrict__ W1,
    const float* __restrict__ W2,
    float* __restrict__ O0, float* __restrict__ O1, float* __restrict__ O2,
    const int nk) {
  const int tid = threadIdx.x;
  const int bx = blockIdx.x;
  const int by = blockIdx.y;
  const int kz = blockIdx.z;
  const int mat = by >> 2;
  const int cb0 = (by & 3) * 64;
  const int rb0 = bx * 32;
  const int kk0 = kz * 64 * nk;
  const float* __restrict__ W = (mat == 0) ? W0 : (mat == 1) ? W1 : W2;
  float* __restrict__ O = ((mat == 0) ? O0 : (mat == 1) ? O1 : O2) + (size_t)kz * NEc;

  __shared__ float Xs[64][36];   // [k][row]
  __shared__ float Ws[64][68];   // [k][col]

  const int f4 = tid & 15;
  const int sub = tid >> 4;
  const int ty = tid >> 4;
  const int tx = tid & 15;

  float acc[4][4];
#pragma unroll
  for (int i = 0; i < 4; ++i)
#pragma unroll
    for (int j = 0; j < 4; ++j) acc[i][j] = 0.f;

  for (int c = 0; c < nk; ++c) {
    const int kk = kk0 + c * 64;
    __syncthreads();
#pragma unroll
    for (int i = 0; i < 4; ++i) {
      int row = sub + i * 8;
      float4 v = *(const float4*)&X[(size_t)(rb0 + row) * Ec + kk + f4 * 4];
      Xs[f4 * 4 + 0][row] = v.x;
      Xs[f4 * 4 + 1][row] = v.y;
      Xs[f4 * 4 + 2][row] = v.z;
      Xs[f4 * 4 + 3][row] = v.w;
    }
#pragma unroll
    for (int i = 0; i < 8; ++i) {
      int col = sub + i * 8;
      float4 v = *(const float4*)&W[(size_t)(cb0 + col) * Ec + kk + f4 * 4];
      Ws[f4 * 4 + 0][col] = v.x;
      Ws[f4 * 4 + 1][col] = v.y;
      Ws[f4 * 4 + 2][col] = v.z;
      Ws[f4 * 4 + 3][col] = v.w;
    }
    __syncthreads();
#pragma unroll 8
    for (int k = 0; k < 64; ++k) {
      float4 a = *(const float4*)&Xs[k][ty * 4];
      float4 b = *(const float4*)&Ws[k][tx * 4];
      float av[4] = {a.x, a.y, a.z, a.w};
      float bv[4] = {b.x, b.y, b.z, b.w};
#pragma unroll
      for (int i = 0; i < 4; ++i)
#pragma unroll
        for (int j = 0; j < 4; ++j) acc[i][j] = fmaf(av[i], bv[j], acc[i][j]);
    }
  }
#pragma unroll
  for (int i = 0; i < 4; ++i) {
    float4 o = make_float4(acc[i][0], acc[i][1], acc[i][2], acc[i][3]);
    *(float4*)&O[(size_t)(rb0 + ty * 4 + i) * Ec + cb0 + tx * 4] = o;
  }
}

// ---------------------------------------------------------------------------
// Per-row hyp_linear epilogue for q/k/v (sums the KSQ K-split partials)
// ---------------------------------------------------------------------------
__global__ __launch_bounds__(256) void qkv_stats(
    const float* __restrict__ x,
    const float* __restrict__ mxq, const float* __restrict__ mxk,
    const float* __restrict__ mxv,
    const float* __restrict__ bq, const float* __restrict__ bk,
    const float* __restrict__ bv,
    float* __restrict__ qo, float* __restrict__ ko, float* __restrict__ lvo,
    float* __restrict__ qno, float* __restrict__ kno) {
  const int t = threadIdx.x;
  const int row = blockIdx.x;
  const int b = row >> 9;
  const int s = row & (Sc - 1);
  const size_t idx = (size_t)row * Ec + t;
  const float xv = x[idx];
  float mq = 0.f, mk = 0.f, mv = 0.f;
#pragma unroll
  for (int p = 0; p < KSQ; ++p) {
    mq += mxq[idx + (size_t)p * NEc];
    mk += mxk[idx + (size_t)p * NEc];
    mv += mxv[idx + (size_t)p * NEc];
  }
  const float bb[3] = {bq[t], bk[t], bv[t]};
  const float mvals[3] = {mq, mk, mv};

  float vals[10] = {xv * xv,
                    mq * mq, mq * bb[0], bb[0] * bb[0],
                    mk * mk, mk * bb[1], bb[1] * bb[1],
                    mv * mv, mv * bb[2], bb[2] * bb[2]};
  __shared__ float red[10][4];
  __shared__ float fin[10];
#pragma unroll
  for (int i = 0; i < 10; ++i) {
    float v = fullWaveSum(vals[i]);
    if ((t & 63) == 0) red[i][t >> 6] = v;
  }
  __syncthreads();
  if (t < 10) fin[t] = red[t][0] + red[t][1] + red[t][2] + red[t][3];
  __syncthreads();

  const float x2 = fin[0];
  const float xn = sqrtf(fmaxf(x2, 1e-15f));
  const float at = atanh_fast(fminf(xn, MAXNORM));  // SC = 1
  const int h = t >> 5;

#pragma unroll
  for (int m = 0; m < 3; ++m) {
    float mx2 = fin[1 + 3 * m];
    float mxb = fin[2 + 3 * m];
    float b2 = fin[3 + 3 * m];
    float mxn = sqrtf(fmaxf(mx2, 1e-15f));
    float scl = tanh_fast((mxn / xn) * at) / mxn;
    float mvv = scl * mvals[m];
    float X2 = scl * scl * mx2;
    float XY = scl * mxb;
    float numc = 1.0f + 2.0f * XY + b2;
    float den = 1.0f + 2.0f * XY + X2 * b2 + 1e-15f;
    float res = (numc * mvv + (1.0f - X2) * bb[m]) / den;
    if (m < 2) {
      res = fminf(res, MAXNORM);                 // elementwise clamp_max
      float s2 = halfWaveSum(res * res);         // per-head ||.||^2 (C=1)
      if (m == 0) {
        qo[idx] = res;
        if ((t & 31) == 0) qno[(b * Hc + h) * Sc + s] = s2;
      } else {
        ko[idx] = res;
        if ((t & 31) == 0) kno[(b * Hc + h) * Sc + s] = s2;
      }
    } else {
      float vn2 = halfWaveSum(res * res);
      float vn = sqrtf(fmaxf(vn2, 1e-15f));
      float f = atanh_fast(fminf(vn, MAXNORM)) / vn;  // logmap0 factor
      lvo[idx] = f * res;
    }
  }
}

// ---------------------------------------------------------------------------
// Fused attention v2: per block = 16 q-rows of one (b,h); 4 k-tiles of 128.
// QK: Kst transposed [d][col] so one b128 = 4 k-cols; Q in registers
// (2 rows x 32d per thread) -> 2 B/FMA outer product, 32 b128 reads/tile.
// PV: old-pv structure (js/rg/dq slicing, float4 x float4, accm merge),
// 2 B/FMA, 32 b128 reads/tile. p in (0,1] -> plain num/den, no online max.
// grid (32 sq-tiles, 16 bh) = 512 blocks, blk 256, LDS 62 KB (2 blk/CU).
// ---------------------------------------------------------------------------
__global__ __launch_bounds__(256, 2) void attn_fused(
    const float* __restrict__ q, const float* __restrict__ k,
    const float* __restrict__ lv, const float* __restrict__ qn,
    const float* __restrict__ kn, const float* __restrict__ hs,
    float* __restrict__ out) {
  const int tid = threadIdx.x;
  const int sq0 = blockIdx.x * 16;
  const int bh = blockIdx.y;
  const int b = bh >> 3;
  const int h = bh & 7;

  __shared__ float Qst[16][36];      // q staging (row-major), then to regs
  __shared__ float Kst[32][132];     // [d][col] transposed k-tile
  __shared__ float LVs[128][36];     // [j][d] row-major lv-tile
  __shared__ float Pst[16][132];     // [r][j] p-tile
  __shared__ float knS[128];
  __shared__ float accm[16][8][32];  // [row][js][d] PV partial merge
  __shared__ float lsb[16][9];       // [row][js] denominator partials

  // QK mapping: 2 rows x 4 cols per thread
  const int r2 = tid >> 5;           // 0..7 -> rows 2*r2, 2*r2+1
  const int c4 = tid & 31;           // 0..31 -> cols c4*4..+3
  // PV mapping (old pv): 4 rows x 4 dims x 16 j per thread
  const int js = tid >> 5;           // 0..7 j-slices of 16
  const int rg = (tid >> 3) & 3;     // row-quad
  const int dq = tid & 7;            // dim-quad
  // staging: row rr, dim-half
  const int rr = tid >> 1;           // 0..127
  const int half = tid & 1;

  // ---- stage Q tile, move to registers ----
  if (tid < 128) {
    int qr = tid >> 3, dqq = tid & 7;
    *(float4*)&Qst[qr][dqq * 4] =
        *(const float4*)&q[(size_t)(b * Sc + sq0 + qr) * Ec + h * Dc + dqq * 4];
  }
  __syncthreads();
  float4 qv0[8], qv1[8];
#pragma unroll
  for (int fd = 0; fd < 8; ++fd) {
    qv0[fd] = *(const float4*)&Qst[2 * r2 + 0][fd * 4];
    qv1[fd] = *(const float4*)&Qst[2 * r2 + 1][fd * 4];
  }
  const float q20 = qn[bh * Sc + sq0 + 2 * r2];
  const float q21 = qn[bh * Sc + sq0 + 2 * r2 + 1];
  const float omq0 = 1.0f - q20;
  const float omq1 = 1.0f - q21;
  const float sinv = -1.0f / (hs[h] * sqrtf((float)Dc));

  float4 acc[4];
#pragma unroll
  for (int i = 0; i < 4; ++i) acc[i] = make_float4(0.f, 0.f, 0.f, 0.f);
  float lsum4[4] = {0.f, 0.f, 0.f, 0.f};

  for (int t = 0; t < NT; ++t) {
    const int j0g = t * KT;
    __syncthreads();   // prior tile's QK/PV reads of Kst/LVs/knS complete
    // ---- stage K (transposed) + LV (row-major) + kn ----
    {
      const size_t gbase = (size_t)(b * Sc + j0g + rr) * Ec + h * Dc;
#pragma unroll
      for (int i = 0; i < 4; ++i) {
        const int dqq = half * 4 + i;
        float4 kv = *(const float4*)&k[gbase + dqq * 4];
        Kst[dqq * 4 + 0][rr] = kv.x;
        Kst[dqq * 4 + 1][rr] = kv.y;
        Kst[dqq * 4 + 2][rr] = kv.z;
        Kst[dqq * 4 + 3][rr] = kv.w;
        *(float4*)&LVs[rr][dqq * 4] = *(const float4*)&lv[gbase + dqq * 4];
      }
      if (tid < 128) knS[tid] = kn[bh * Sc + j0g + tid];
    }
    __syncthreads();   // staged tile visible

    // ---- QK: p[2 rows][4 cols] over d=32, 4 b128 per fd-group ----
    float p0[4] = {0.f, 0.f, 0.f, 0.f};
    float p1[4] = {0.f, 0.f, 0.f, 0.f};
#pragma unroll
    for (int fd = 0; fd < 8; ++fd) {
      float4 k0 = *(const float4*)&Kst[fd * 4 + 0][c4 * 4];
      float4 k1 = *(const float4*)&Kst[fd * 4 + 1][c4 * 4];
      float4 k2 = *(const float4*)&Kst[fd * 4 + 2][c4 * 4];
      float4 k3 = *(const float4*)&Kst[fd * 4 + 3][c4 * 4];
      float4 a0 = qv0[fd];
      float4 a1 = qv1[fd];
      p0[0] = fmaf(a0.x, k0.x, p0[0]); p0[0] = fmaf(a0.y, k1.x, p0[0]);
      p0[0] = fmaf(a0.z, k2.x, p0[0]); p0[0] = fmaf(a0.w, k3.x, p0[0]);
      p0[1] = fmaf(a0.x, k0.y, p0[1]); p0[1] = fmaf(a0.y, k1.y, p0[1]);
      p0[1] = fmaf(a0.z, k2.y, p0[1]); p0[1] = fmaf(a0.w, k3.y, p0[1]);
      p0[2] = fmaf(a0.x, k0.z, p0[2]); p0[2] = fmaf(a0.y, k1.z, p0[2]);
      p0[2] = fmaf(a0.z, k2.z, p0[2]); p0[2] = fmaf(a0.w, k3.z, p0[2]);
      p0[3] = fmaf(a0.x, k0.w, p0[3]); p0[3] = fmaf(a0.y, k1.w, p0[3]);
      p0[3] = fmaf(a0.z, k2.w, p0[3]); p0[3] = fmaf(a0.w, k3.w, p0[3]);
      p1[0] = fmaf(a1.x, k0.x, p1[0]); p1[0] = fmaf(a1.y, k1.x, p1[0]);
      p1[0] = fmaf(a1.z, k2.x, p1[0]); p1[0] = fmaf(a1.w, k3.x, p1[0]);
      p1[1] = fmaf(a1.x, k0.y, p1[1]); p1[1] = fmaf(a1.y, k1.y, p1[1]);
      p1[1] = fmaf(a1.z, k2.y, p1[1]); p1[1] = fmaf(a1.w, k3.y, p1[1]);
      p1[2] = fmaf(a1.x, k0.z, p1[2]); p1[2] = fmaf(a1.y, k1.z, p1[2]);
      p1[2] = fmaf(a1.z, k2.z, p1[2]); p1[2] = fmaf(a1.w, k3.z, p1[2]);
      p1[3] = fmaf(a1.x, k0.w, p1[3]); p1[3] = fmaf(a1.y, k1.w, p1[3]);
      p1[3] = fmaf(a1.z, k2.w, p1[3]); p1[3] = fmaf(a1.w, k3.w, p1[3]);
    }

    // ---- epilogue: hyperbolic distance -> p = z^sinv ----
    float4 k2v = *(const float4*)&knS[c4 * 4];
    const float kk2[4] = {k2v.x, k2v.y, k2v.z, k2v.w};
    {
      float po[4];
#pragma unroll
      for (int j = 0; j < 4; ++j) {
        const float k2 = kk2[j];
        const float kq = p0[j];
        const float omk = 1.0f - k2;
        float s2x2 = fmaf(-4.0f, kq, 2.0f * k2 + 2.0f * q20);
        float dden = fmaf(k2, q20, fmaf(-2.0f, kq, 1.0f)) + 1e-15f;
        float Pd = fmaf(dden, omk * omq0, 1e-20f);
        float rp = __builtin_amdgcn_rcpf(Pd);
        float tt = fmaxf(s2x2 * rp, 1e-7f);                    // a-1
        float z = (1.0f + tt) + sqrtf(fmaf(tt, tt, tt + tt));
        po[j] = __builtin_amdgcn_exp2f(sinv * __builtin_amdgcn_logf(z));
      }
      *(float4*)&Pst[2 * r2 + 0][c4 * 4] = make_float4(po[0], po[1], po[2], po[3]);
    }
    {
      float po[4];
#pragma unroll
      for (int j = 0; j < 4; ++j) {
        const float k2 = kk2[j];
        const float kq = p1[j];
        const float omk = 1.0f - k2;
        float s2x2 = fmaf(-4.0f, kq, 2.0f * k2 + 2.0f * q21);
        float dden = fmaf(k2, q21, fmaf(-2.0f, kq, 1.0f)) + 1e-15f;
        float Pd = fmaf(dden, omk * omq1, 1e-20f);
        float rp = __builtin_amdgcn_rcpf(Pd);
        float tt = fmaxf(s2x2 * rp, 1e-7f);
        float z = (1.0f + tt) + sqrtf(fmaf(tt, tt, tt + tt));
        po[j] = __builtin_amdgcn_exp2f(sinv * __builtin_amdgcn_logf(z));
      }
      *(float4*)&Pst[2 * r2 + 1][c4 * 4] = make_float4(po[0], po[1], po[2], po[3]);
    }
    __syncthreads();   // Pst complete

    // ---- PV: acc[4 rows][4 dims] += P[rows][j] * LV[j][dims], j in js-slice
#pragma unroll
    for (int j4 = 0; j4 < 4; ++j4) {
      const int jl = js * 16 + j4 * 4;
      float4 p[4], l[4];
#pragma unroll
      for (int i = 0; i < 4; ++i) p[i] = *(const float4*)&Pst[rg * 4 + i][jl];
#pragma unroll
      for (int c = 0; c < 4; ++c) l[c] = *(const float4*)&LVs[jl + c][dq * 4];
#pragma unroll
      for (int i = 0; i < 4; ++i) {
        lsum4[i] += (p[i].x + p[i].y) + (p[i].z + p[i].w);
        acc[i].x = fmaf(p[i].x, l[0].x, acc[i].x);
        acc[i].y = fmaf(p[i].x, l[0].y, acc[i].y);
        acc[i].z = fmaf(p[i].x, l[0].z, acc[i].z);
        acc[i].w = fmaf(p[i].x, l[0].w, acc[i].w);
        acc[i].x = fmaf(p[i].y, l[1].x, acc[i].x);
        acc[i].y = fmaf(p[i].y, l[1].y, acc[i].y);
        acc[i].z = fmaf(p[i].y, l[1].z, acc[i].z);
        acc[i].w = fmaf(p[i].y, l[1].w, acc[i].w);
        acc[i].x = fmaf(p[i].z, l[2].x, acc[i].x);
        acc[i].y = fmaf(p[i].z, l[2].y, acc[i].y);
        acc[i].z = fmaf(p[i].z, l[2].z, acc[i].z);
        acc[i].w = fmaf(p[i].z, l[2].w, acc[i].w);
        acc[i].x = fmaf(p[i].w, l[3].x, acc[i].x);
        acc[i].y = fmaf(p[i].w, l[3].y, acc[i].y);
        acc[i].z = fmaf(p[i].w, l[3].z, acc[i].z);
        acc[i].w = fmaf(p[i].w, l[3].w, acc[i].w);
      }
    }
    // no trailing barrier: next iteration's top barrier orders restaging
  }

  // ---- merge js partials (old-pv ending) ----
#pragma unroll
  for (int i = 0; i < 4; ++i)
    *(float4*)&accm[rg * 4 + i][js][dq * 4] = acc[i];
  if (dq == 0) {
#pragma unroll
    for (int i = 0; i < 4; ++i) lsb[rg * 4 + i][js] = lsum4[i];
  }
  __syncthreads();

  const int r2e = tid >> 4;      // 0..15 (row)
  const int dd = tid & 15;       // 0..15, 2 dims each
  float o0 = 0.f, o1 = 0.f, ls = 0.f;
#pragma unroll
  for (int g = 0; g < 8; ++g) {
    float2 a2 = *(const float2*)&accm[r2e][g][dd * 2];
    o0 += a2.x;
    o1 += a2.y;
    ls += lsb[r2e][g];
  }
  const float li = 1.0f / ls;
  o0 *= li;
  o1 *= li;
  float un2 = fmaf(o0, o0, o1 * o1);
#pragma unroll
  for (int m = 8; m >= 1; m >>= 1) un2 += __shfl_xor(un2, m, 16);
  float un = sqrtf(fmaxf(un2, 1e-15f));
  float f = tanh_fast(un) / un;        // expmap0 factor (SC = 1)
  float2 ov = make_float2(o0 * f, o1 * f);
  *(float2*)&out[(size_t)(b * Sc + sq0 + r2e) * Ec + h * Dc + dd * 2] = ov;
}

// ---------------------------------------------------------------------------
// Per-row hyp_linear epilogue for the output projection (sums KSO partials)
// ---------------------------------------------------------------------------
__global__ __launch_bounds__(256) void proj_stats(
    const float* __restrict__ xin, const float* __restrict__ mx,
    const float* __restrict__ bo, float* __restrict__ out) {
  const int t = threadIdx.x;
  const int row = blockIdx.x;
  const size_t idx = (size_t)row * Ec + t;
  const float xv = xin[idx];
  float m = 0.f;
#pragma unroll
  for (int p = 0; p < KSO; ++p) m += mx[idx + (size_t)p * NEc];
  const float bb = bo[t];
  float vals[4] = {xv * xv, m * m, m * bb, bb * bb};
  __shared__ float red[4][4];
  __shared__ float fin[4];
#pragma unroll
  for (int i = 0; i < 4; ++i) {
    float v = fullWaveSum(vals[i]);
    if ((t & 63) == 0) red[i][t >> 6] = v;
  }
  __syncthreads();
  if (t < 4) fin[t] = red[t][0] + red[t][1] + red[t][2] + red[t][3];
  __syncthreads();

  float x2 = fin[0], mx2 = fin[1], mxb = fin[2], b2 = fin[3];
  float xn = sqrtf(fmaxf(x2, 1e-15f));
  float mxn = sqrtf(fmaxf(mx2, 1e-15f));
  float scl = tanh_fast((mxn / xn) * atanh_fast(fminf(xn, MAXNORM))) / mxn;
  float mvv = scl * m;
  float X2 = scl * scl * mx2;
  float XY = scl * mxb;
  float numc = 1.0f + 2.0f * XY + b2;
  float den = 1.0f + 2.0f * XY + X2 * b2 + 1e-15f;
  out[idx] = (numc * mvv + (1.0f - X2) * bb) / den;
}

extern "C" void kernel_launch(void* const* d_in, const int* in_sizes, int n_in,
                              void* d_out, int out_size, void* d_ws, size_t ws_size,
                              hipStream_t stream) {
  (void)in_sizes; (void)n_in; (void)out_size; (void)ws_size;
  const float* x  = (const float*)d_in[0];
  const float* Wq = (const float*)d_in[1];
  const float* bq = (const float*)d_in[2];
  const float* Wk = (const float*)d_in[3];
  const float* bk = (const float*)d_in[4];
  const float* Wv = (const float*)d_in[5];
  const float* bv = (const float*)d_in[6];
  const float* Wo = (const float*)d_in[7];
  const float* bo = (const float*)d_in[8];
  const float* hs = (const float*)d_in[9];

  float* ws = (float*)d_ws;
  const int NE = NEc;            // 262144
  const int NH = NROWS;          // 8192
  float* mxq = ws;               // KSQ*NE partials each
  float* mxk = mxq + KSQ * NE;
  float* mxv = mxk + KSQ * NE;
  float* mxo = mxv + KSQ * NE;   // KSO*NE partials
  float* qb  = mxo + KSO * NE;
  float* kb  = qb + NE;
  float* lvb = kb + NE;
  float* aob = lvb + NE;
  float* qnb = aob + NE;
  float* knb = qnb + NH;

  const int M = Bc * Sc;  // 1024 rows

  gemm_xwt<<<dim3(M / 32, 12, KSQ), 128, 0, stream>>>(x, Wq, Wk, Wv,
                                                      mxq, mxk, mxv, 2);
  qkv_stats<<<M, 256, 0, stream>>>(x, mxq, mxk, mxv, bq, bk, bv,
                                   qb, kb, lvb, qnb, knb);
  attn_fused<<<dim3(32, 16), 256, 0, stream>>>(qb, kb, lvb, qnb, knb, hs, aob);
  gemm_xwt<<<dim3(M / 32, 4, KSO), 128, 0, stream>>>(aob, Wo, Wo, Wo,
                                                     mxo, mxo, mxo, 1);
  proj_stats<<<M, 256, 0, stream>>>(aob, mxo, bo, (float*)d_out);
}